// Round 2
// baseline (404.616 us; speedup 1.0000x reference)
//
#include <hip/hip_runtime.h>
#include <stdint.h>

// ---------- types & helpers ----------
using f32x4  = __attribute__((ext_vector_type(4))) float;
using bf16x8 = __attribute__((ext_vector_type(8))) short;
using u16x4  = __attribute__((ext_vector_type(4))) ushort;

#define MFMA16(a, b, c) __builtin_amdgcn_mfma_f32_16x16x32_bf16((a), (b), (c), 0, 0, 0)

__device__ __forceinline__ void gload_lds16(const void* g, void* l) {
    __builtin_amdgcn_global_load_lds(
        (const __attribute__((address_space(1))) void*)g,
        (__attribute__((address_space(3))) void*)l, 16, 0, 0);
}

__device__ __forceinline__ ushort f2bf(float f) {
    union { float f; uint32_t u; } v; v.f = f;
    uint32_t r = v.u + 0x7fffu + ((v.u >> 16) & 1u);
    return (ushort)(r >> 16);
}

#define NEG_BIG (-1.0e30f)

// ---------- pack f32 -> bf16 ----------
__global__ void pack_bf16_k(const float* __restrict__ in, ushort* __restrict__ out, int n4) {
    const int i = blockIdx.x * blockDim.x + threadIdx.x;
    if (i >= n4) return;
    const f32x4 v = *(const f32x4*)(in + (size_t)i * 4);
    u16x4 o;
    o[0] = f2bf(v[0]); o[1] = f2bf(v[1]); o[2] = f2bf(v[2]); o[3] = f2bf(v[3]);
    *(u16x4*)(out + (size_t)i * 4) = o;
}

// ---------- weight transpose: f32 in [R][C] -> bf16 out [C][R] ----------
__global__ void transpose_k(const float* __restrict__ in, ushort* __restrict__ out,
                            int R, int C) {
    __shared__ ushort tile[32][33];
    const int c0 = blockIdx.x * 32, r0 = blockIdx.y * 32;
    const int tx = threadIdx.x, ty = threadIdx.y;
    for (int i = ty; i < 32; i += 8)
        tile[i][tx] = f2bf(in[(size_t)(r0 + i) * C + c0 + tx]);
    __syncthreads();
    for (int i = ty; i < 32; i += 8)
        out[(size_t)(c0 + i) * R + r0 + tx] = tile[tx][i];
}

// ---------- m97-structure GEMM: C[M,N] = A[M,K] @ BT[N,K]^T + bias ----------
// MODE 0: f32 out (proj GEMM -> d_out), row stride N
// MODE 1: QKV split: cols [0,2048) -> qk buffer bf16 (stride 2048),
//         cols [2048,3072) -> V transposed bf16 vt[bh][d][t]
template <int MODE>
__global__ __launch_bounds__(256, 2)
void gemm_bt(const ushort* __restrict__ A, const ushort* __restrict__ BT,
             const float* __restrict__ bias, float* __restrict__ outF,
             ushort* __restrict__ qk, ushort* __restrict__ vt,
             int M, int N, int K) {
    __shared__ __align__(16) ushort As[128 * 32];
    __shared__ __align__(16) ushort Bs[128 * 32];
    const int tid  = threadIdx.x;
    const int lane = tid & 63;
    const int wid  = tid >> 6;
    const int l15  = lane & 15, lg = lane >> 4;
    const int tile_m = blockIdx.x * 128;
    const int tile_n = blockIdx.y * 128;
    const int wm = (wid >> 1) * 64;
    const int wn = (wid & 1) * 64;

    const f32x4 fzero = {0.f, 0.f, 0.f, 0.f};
    f32x4 acc[4][4];
#pragma unroll
    for (int i = 0; i < 4; ++i)
#pragma unroll
        for (int j = 0; j < 4; ++j) acc[i][j] = fzero;

    const int c0 = tid & 3;
    const int r0 = tid >> 2;                 // 0..63
    const ushort* Arow0 = A  + (size_t)(tile_m + r0)      * K + c0 * 8;
    const ushort* Arow1 = A  + (size_t)(tile_m + 64 + r0) * K + c0 * 8;
    const ushort* Brow0 = BT + (size_t)(tile_n + r0)      * K + c0 * 8;
    const ushort* Brow1 = BT + (size_t)(tile_n + 64 + r0) * K + c0 * 8;
    const int ldsb0 = (wid * 64) * 16;
    const int ldsb1 = (256 + wid * 64) * 16;

    for (int k0 = 0; k0 < K; k0 += 32) {
        gload_lds16(Arow0 + k0, (char*)As + ldsb0);
        gload_lds16(Arow1 + k0, (char*)As + ldsb1);
        gload_lds16(Brow0 + k0, (char*)Bs + ldsb0);
        gload_lds16(Brow1 + k0, (char*)Bs + ldsb1);
        __syncthreads();

        bf16x8 af[4], bfv[4];
#pragma unroll
        for (int mf = 0; mf < 4; ++mf)
            af[mf] = *(const bf16x8*)&As[(wm + mf * 16 + l15) * 32 + lg * 8];
#pragma unroll
        for (int nf = 0; nf < 4; ++nf)
            bfv[nf] = *(const bf16x8*)&Bs[(wn + nf * 16 + l15) * 32 + lg * 8];
#pragma unroll
        for (int mf = 0; mf < 4; ++mf)
#pragma unroll
            for (int nf = 0; nf < 4; ++nf)
                acc[mf][nf] = MFMA16(af[mf], bfv[nf], acc[mf][nf]);
        __syncthreads();
    }

    // epilogue: C row = tile_m+wm+mf*16+(lg*4+i), col = tile_n+wn+nf*16+l15
#pragma unroll
    for (int nf = 0; nf < 4; ++nf) {
        const int col = tile_n + wn + nf * 16 + l15;
        const float bv = bias[col];
#pragma unroll
        for (int mf = 0; mf < 4; ++mf) {
#pragma unroll
            for (int i = 0; i < 4; ++i) {
                const int row = tile_m + wm + mf * 16 + lg * 4 + i;
                const float val = acc[mf][nf][i] + bv;
                if (MODE == 0) {
                    outF[(size_t)row * N + col] = val;
                } else {
                    if (col < 2048) {
                        qk[(size_t)row * 2048 + col] = f2bf(val);
                    } else {
                        const int vc = col - 2048;
                        const int bb = row >> 11, t = row & 2047;
                        vt[((size_t)(bb * 16 + (vc >> 6)) * 64 + (vc & 63)) * 2048 + t] = f2bf(val);
                    }
                }
            }
        }
    }
}

// ---------- causal flash attention ----------
// qk: [B*T][2048] bf16 (q cols 0..1023, k cols 1024..2047, head h at h*64)
// vt: [B*NH][64][2048] bf16 (V transposed)
// ao: [B*T][1024] bf16
// grid: (qblock 32, bh 64), block 256 (4 waves x 16 q-rows)
__global__ __launch_bounds__(256, 2)
void attn_fwd(const ushort* __restrict__ qk, const ushort* __restrict__ vt,
              ushort* __restrict__ ao) {
    const int tid  = threadIdx.x;
    const int lane = tid & 63;
    const int w    = tid >> 6;
    const int l15  = lane & 15, lg = lane >> 4;
    const int bh = blockIdx.y;
    const int b = bh >> 4, h = bh & 15;
    const int q0 = blockIdx.x * 64;
    const int qw = q0 + w * 16;                 // this wave's first q row

    __shared__ __align__(16) ushort Ks[32 * 64];     // [kv][d], rows XOR-swizzled
    __shared__ __align__(16) ushort Vs[64 * 32];     // [d][kv], chunks XOR-swizzled
    __shared__ __align__(16) ushort Ps[4][16 * 40];  // per-wave P [q][kv], pad to 40

    // hoisted Q B-fragments: lane holds Q[qw+l15][dc*32 + lg*8 + j]
    const ushort* qbase = qk + ((size_t)(b * 2048 + qw + l15)) * 2048 + h * 64;
    bf16x8 qf[2];
    qf[0] = *(const bf16x8*)(qbase + lg * 8);
    qf[1] = *(const bf16x8*)(qbase + 32 + lg * 8);

    const f32x4 fzero = {0.f, 0.f, 0.f, 0.f};
    f32x4 o[4];
#pragma unroll
    for (int f = 0; f < 4; ++f) o[f] = fzero;
    float m_run = NEG_BIG, l_run = 0.f;
    const float sscale = 0.125f * 1.4426950408889634f;  // HD^-0.5 * log2(e)

    const ushort* kbase = qk + (size_t)b * 2048 * 2048 + 1024 + h * 64;
    const ushort* vbase = vt + (size_t)bh * 64 * 2048;

    // staging coords (source pre-swizzled so linear LDS dest = swizzled layout)
    const int krow   = (w * 64 + lane) >> 3;                 // 0..31 (128B rows, 8 chunks)
    const int kchunk = (lane & 7) ^ (krow & 7);
    const int vrow_s = (w * 64 + lane) >> 2;                 // 0..63 (64B rows, 4 chunks)
    const int vchunk = (lane & 3) ^ ((vrow_s >> 1) & 3);
    const int ldsoff = (w * 64) * 16;

    const int nsteps = q0 / 32 + 2;
    for (int s = 0; s < nsteps; ++s) {
        const int kv0 = s * 32;
        gload_lds16(kbase + (size_t)(kv0 + krow) * 2048 + kchunk * 8, (char*)Ks + ldsoff);
        gload_lds16(vbase + (size_t)vrow_s * 2048 + kv0 + vchunk * 8, (char*)Vs + ldsoff);
        __syncthreads();

        // S^T = K . Q  (swapped: q ends up in lane&15)
        f32x4 st[2] = {fzero, fzero};
#pragma unroll
        for (int dc = 0; dc < 2; ++dc) {
#pragma unroll
            for (int hh = 0; hh < 2; ++hh) {
                const int row = hh * 16 + l15;
                int byte_off = row * 128 + dc * 64 + lg * 16;
                byte_off ^= (row & 7) << 4;
                const bf16x8 kf = *(const bf16x8*)((const char*)Ks + byte_off);
                st[hh] = MFMA16(kf, qf[dc], st[hh]);
            }
        }

        // scale + causal mask; lane holds S^T[kv0+hh*16+lg*4+i][qw+l15]
        const int qg = qw + l15;
        float sv[8];
#pragma unroll
        for (int hh = 0; hh < 2; ++hh)
#pragma unroll
            for (int i = 0; i < 4; ++i) {
                const int kvg = kv0 + hh * 16 + lg * 4 + i;
                const float x = st[hh][i] * sscale;
                sv[hh * 4 + i] = (kvg > qg) ? NEG_BIG : x;
            }

        // online softmax (per q row = l15; reduce across lg groups)
        float mt = sv[0];
#pragma unroll
        for (int j = 1; j < 8; ++j) mt = fmaxf(mt, sv[j]);
        mt = fmaxf(mt, __shfl_xor(mt, 16));
        mt = fmaxf(mt, __shfl_xor(mt, 32));
        const float mn = fmaxf(m_run, mt);
        const float alpha = exp2f(m_run - mn);
        float ps[8]; float rs = 0.f;
#pragma unroll
        for (int j = 0; j < 8; ++j) { ps[j] = exp2f(sv[j] - mn); rs += ps[j]; }
        rs += __shfl_xor(rs, 16);
        rs += __shfl_xor(rs, 32);
        l_run = l_run * alpha + rs;
        m_run = mn;

        // rescale O (O rows are q = lg*4+i -> fetch alpha from lane q)
        float ar[4];
#pragma unroll
        for (int i = 0; i < 4; ++i) ar[i] = __shfl(alpha, lg * 4 + i);
#pragma unroll
        for (int f = 0; f < 4; ++f)
#pragma unroll
            for (int i = 0; i < 4; ++i) o[f][i] *= ar[i];

        // P^T -> Ps[w] as [q][kv] (pack 4 bf16 = one 8B write per half)
#pragma unroll
        for (int hh = 0; hh < 2; ++hh) {
            uint2 pk;
            pk.x = (uint32_t)f2bf(ps[hh * 4 + 0]) | ((uint32_t)f2bf(ps[hh * 4 + 1]) << 16);
            pk.y = (uint32_t)f2bf(ps[hh * 4 + 2]) | ((uint32_t)f2bf(ps[hh * 4 + 3]) << 16);
            *(uint2*)&Ps[w][l15 * 40 + hh * 16 + lg * 4] = pk;
        }
        // P A-fragment: lane holds P[q=l15][kv=lg*8..+7]
        const bf16x8 pf = *(const bf16x8*)&Ps[w][l15 * 40 + lg * 8];

        // O += P.V : B-frag from V^T LDS (swizzled chunks)
#pragma unroll
        for (int f = 0; f < 4; ++f) {
            const int vrow = f * 16 + l15;
            const int byte_off = vrow * 64 + ((lg ^ ((vrow >> 1) & 3)) * 16);
            const bf16x8 vf = *(const bf16x8*)((const char*)Vs + byte_off);
            o[f] = MFMA16(pf, vf, o[f]);
        }
        __syncthreads();
    }

    // epilogue: divide by l and store
    float lr[4];
#pragma unroll
    for (int i = 0; i < 4; ++i) lr[i] = __shfl(l_run, lg * 4 + i);
#pragma unroll
    for (int f = 0; f < 4; ++f)
#pragma unroll
        for (int i = 0; i < 4; ++i) {
            const int row = qw + lg * 4 + i;
            const int col = h * 64 + f * 16 + l15;
            ao[((size_t)(b * 2048 + row)) * 1024 + col] = f2bf(o[f][i] / lr[i]);
        }
}

// ---------- launch ----------
extern "C" void kernel_launch(void* const* d_in, const int* in_sizes, int n_in,
                              void* d_out, int out_size, void* d_ws, size_t ws_size,
                              hipStream_t stream) {
    const float* x      = (const float*)d_in[0];
    const float* w_attn = (const float*)d_in[1];
    const float* b_attn = (const float*)d_in[2];
    const float* w_proj = (const float*)d_in[3];
    const float* b_proj = (const float*)d_in[4];
    float* out = (float*)d_out;

    ushort* ws  = (ushort*)d_ws;
    ushort* xb  = ws;                                   // 8192*1024
    ushort* wTa = xb  + (size_t)8192 * 1024;            // 3072*1024
    ushort* wTp = wTa + (size_t)3072 * 1024;            // 1024*1024
    ushort* qkb = wTp + (size_t)1024 * 1024;            // 8192*2048
    ushort* vtb = qkb + (size_t)8192 * 2048;            // 64*64*2048
    ushort* aob = vtb + (size_t)64 * 64 * 2048;         // 8192*1024
    const size_t needed = ((size_t)8192 * 1024 + (size_t)3072 * 1024 + (size_t)1024 * 1024 +
                           (size_t)8192 * 2048 + (size_t)64 * 64 * 2048 + (size_t)8192 * 1024) * 2;
    if (ws_size < needed) return;  // ws too small -> clean fail (absmax = max|ref|)

    // pack x to bf16
    pack_bf16_k<<<8192, 256, 0, stream>>>(x, xb, 8192 * 1024 / 4);
    // weight transposes (f32 -> bf16)
    transpose_k<<<dim3(96, 32), dim3(32, 8), 0, stream>>>(w_attn, wTa, 1024, 3072);
    transpose_k<<<dim3(32, 32), dim3(32, 8), 0, stream>>>(w_proj, wTp, 1024, 1024);
    // QKV projection (epilogue splits q/k and transposed V)
    gemm_bt<1><<<dim3(64, 24), 256, 0, stream>>>(xb, wTa, b_attn, nullptr, qkb, vtb, 8192, 3072, 1024);
    // causal flash attention
    attn_fwd<<<dim3(32, 64), 256, 0, stream>>>(qkb, vtb, aob);
    // output projection -> f32 out
    gemm_bt<0><<<dim3(64, 8), 256, 0, stream>>>(aob, wTp, b_proj, out, nullptr, nullptr, 8192, 1024, 1024);
}